// Round 1
// baseline (166.291 us; speedup 1.0000x reference)
//
#include <hip/hip_runtime.h>

#define NLEV 8
#define BASE 512
#define FEAT 16

// float offset of mip level k (k>=1) inside ws
__host__ __device__ __forceinline__ long mip_off(int k) {
    return 4194304L - (4194304L >> (2 * k - 2));
}

// Downsample: dst (3, r2, r2, 16) = 2x2 box filter of src (3, 2*r2, 2*r2, 16).
// One thread per float4 feature-group of one output texel.
__global__ __launch_bounds__(256) void ds_kernel(const float* __restrict__ src,
                                                 float* __restrict__ dst, int r2) {
    int idx = blockIdx.x * blockDim.x + threadIdx.x;
    int total = 3 * r2 * r2 * 4;
    if (idx >= total) return;
    int fg = idx & 3;
    int rest = idx >> 2;
    int u = rest % r2; rest /= r2;
    int v = rest % r2;
    int p = rest / r2;
    int rs = r2 * 2;
    const float4* s4 = (const float4*)src;
    long i00 = (((long)p * rs + 2 * v) * rs + 2 * u) * 4 + fg;
    long i01 = i00 + 4;              // u+1
    long i10 = i00 + (long)rs * 4;   // v+1
    long i11 = i10 + 4;
    float4 a = s4[i00], b = s4[i01], c = s4[i10], d = s4[i11];
    float4 o;
    o.x = (a.x + b.x + c.x + d.x) * 0.25f;
    o.y = (a.y + b.y + c.y + d.y) * 0.25f;
    o.z = (a.z + b.z + c.z + d.z) * 0.25f;
    o.w = (a.w + b.w + c.w + d.w) * 0.25f;
    float4* d4 = (float4*)dst;
    d4[(((long)p * r2 + v) * r2 + u) * 4 + fg] = o;
}

// Sampling: 4 threads per point; lane fg owns feature float4 [fg*4 .. fg*4+3].
__global__ __launch_bounds__(256) void tm_sample(const float* __restrict__ x,
                                                 const float* __restrict__ level,
                                                 const float* __restrict__ tex0,
                                                 const float* __restrict__ ws,
                                                 float* __restrict__ out, int n) {
    int t = blockIdx.x * blockDim.x + threadIdx.x;
    int i = t >> 2;
    if (i >= n) return;
    int fg = t & 3;

    float px = x[3 * i + 0];
    float py = x[3 * i + 1];
    float pz = x[3 * i + 2];
    float lev = fminf(fmaxf(level[i], 0.0f), (float)(NLEV - 1));
    float l0f = floorf(lev);
    float frac = lev - l0f;
    int l0 = (int)l0f;

    float uu[3] = {py, px, px};
    float vv[3] = {pz, pz, py};

    float4 acc0 = make_float4(0.f, 0.f, 0.f, 0.f);
    float4 acc1 = make_float4(0.f, 0.f, 0.f, 0.f);
    float4 acc2 = make_float4(0.f, 0.f, 0.f, 0.f);

    for (int s = 0; s < 2; ++s) {
        int k = l0 + s;
        float w = s ? frac : (1.0f - frac);
        if (k >= NLEV || w == 0.0f) continue;
        int r = BASE >> k;
        float rf = (float)r;
        const float* tex = (k == 0) ? tex0 : (ws + mip_off(k));
        const float4* t4 = (const float4*)tex;

#pragma unroll
        for (int p = 0; p < 3; ++p) {
            float cu = uu[p] * rf - 0.5f;
            float cv = vv[p] * rf - 0.5f;
            float fu0 = floorf(cu), fv0 = floorf(cv);
            float fu = cu - fu0, fv = cv - fv0;
            int iu0 = (int)fu0, iv0 = (int)fv0;
            int u0 = min(max(iu0, 0), r - 1);
            int u1 = min(max(iu0 + 1, 0), r - 1);
            int v0 = min(max(iv0, 0), r - 1);
            int v1 = min(max(iv0 + 1, 0), r - 1);
            long pb = (long)p * r * r;
            float4 t00 = t4[(pb + (long)v0 * r + u0) * 4 + fg];
            float4 t01 = t4[(pb + (long)v0 * r + u1) * 4 + fg];
            float4 t10 = t4[(pb + (long)v1 * r + u0) * 4 + fg];
            float4 t11 = t4[(pb + (long)v1 * r + u1) * 4 + fg];
            float wu0 = 1.0f - fu, wv0 = 1.0f - fv;
            float w00 = wu0 * wv0 * w;
            float w01 = fu * wv0 * w;
            float w10 = wu0 * fv * w;
            float w11 = fu * fv * w;
            float4 r4;
            r4.x = t00.x * w00 + t01.x * w01 + t10.x * w10 + t11.x * w11;
            r4.y = t00.y * w00 + t01.y * w01 + t10.y * w10 + t11.y * w11;
            r4.z = t00.z * w00 + t01.z * w01 + t10.z * w10 + t11.z * w11;
            r4.w = t00.w * w00 + t01.w * w01 + t10.w * w11 * 0.0f + t11.w * w11; // placeholder fixed below
            if (p == 0) {
                acc0.x += r4.x; acc0.y += r4.y; acc0.z += r4.z;
                acc0.w += t00.w * w00 + t01.w * w01 + t10.w * w10 + t11.w * w11;
            } else if (p == 1) {
                acc1.x += r4.x; acc1.y += r4.y; acc1.z += r4.z;
                acc1.w += t00.w * w00 + t01.w * w01 + t10.w * w10 + t11.w * w11;
            } else {
                acc2.x += r4.x; acc2.y += r4.y; acc2.z += r4.z;
                acc2.w += t00.w * w00 + t01.w * w01 + t10.w * w10 + t11.w * w11;
            }
        }
    }

    float4* o4 = (float4*)out;
    long ob = (long)i * 12 + fg;
    o4[ob + 0] = acc0;
    o4[ob + 4] = acc1;
    o4[ob + 8] = acc2;
}

extern "C" void kernel_launch(void* const* d_in, const int* in_sizes, int n_in,
                              void* d_out, int out_size, void* d_ws, size_t ws_size,
                              hipStream_t stream) {
    const float* x     = (const float*)d_in[0];
    const float* level = (const float*)d_in[1];
    const float* tex   = (const float*)d_in[2];
    float* out = (float*)d_out;
    float* ws  = (float*)d_ws;
    int n = in_sizes[0] / 3;

    // Build mip pyramid: level k from level k-1.
    const float* src = tex;
    for (int k = 1; k < NLEV; ++k) {
        int r2 = BASE >> k;
        float* dst = ws + mip_off(k);
        int total = 3 * r2 * r2 * 4;
        int blocks = (total + 255) / 256;
        ds_kernel<<<blocks, 256, 0, stream>>>(src, dst, r2);
        src = dst;
    }

    long tt = (long)n * 4;
    int blocks = (int)((tt + 255) / 256);
    tm_sample<<<blocks, 256, 0, stream>>>(x, level, tex, ws, out, n);
}